// Round 8
// baseline (2597.204 us; speedup 1.0000x reference)
//
#include <hip/hip_runtime.h>
#include <hip/hip_bf16.h>

#define T_TOK 4096   // B*S
#define D_DIM 1024
#define N3    3072
#define S_LEN 2048
#define NH    16
#define HD    64

#define OUT_A_ELEMS   4194304   // B*S*D   (f32 elements)
#define OUT_KV_ELEMS  4194304   // B*H*S*hd

// ---------------- K1: lora down-proj  tq = x@q_a1, tv = x@v_a1  ----------------
__global__ __launch_bounds__(64) void lora1_kernel(const float* __restrict__ x,
    const float* __restrict__ qa1, const float* __restrict__ va1,
    float* __restrict__ tq, float* __restrict__ tv) {
    int t = blockIdx.x;
    int lane = threadIdx.x;
    if (lane >= 32) return;
    const float* a1 = (lane < 16) ? qa1 : va1;
    int col = lane & 15;
    const float* xr = x + (size_t)t * D_DIM;
    float acc = 0.f;
#pragma unroll 4
    for (int k = 0; k < D_DIM; ++k)
        acc = fmaf(xr[k], a1[k * 16 + col], acc);
    if (lane < 16) tq[t * 16 + col] = acc;
    else           tv[t * 16 + col] = acc;
}

// ------ K2: qkv = x@W + b (+ lora up); q (pre-scaled 1/8) -> qstage, k/v -> present (f32)
__global__ __launch_bounds__(256) void qkv_kernel(const float* __restrict__ x,
    const float* __restrict__ w, const float* __restrict__ bias,
    const float* __restrict__ qa2, const float* __restrict__ va2,
    const float* __restrict__ tq, const float* __restrict__ tv,
    float* __restrict__ qstage,   // [B,H,S,hd] f32 (aliases a-region of d_out)
    float* __restrict__ pres) {   // [2,B,H,S,hd] f32 (present region of d_out)
    __shared__ float As[128][17];
    __shared__ float Bs[16][64];
    int bx = blockIdx.x;   // 0..47 : one 64-col tile == one (segment, head)
    int by = blockIdx.y;   // 0..31
    int tid = threadIdx.x;
    int tx = tid & 15, ty = tid >> 4;

    float c[8][4];
#pragma unroll
    for (int i = 0; i < 8; ++i)
#pragma unroll
        for (int j = 0; j < 4; ++j) c[i][j] = 0.f;

    for (int k0 = 0; k0 < D_DIM; k0 += 16) {
#pragma unroll
        for (int u = 0; u < 2; ++u) {
            int f4 = tid + 256 * u;           // 0..511
            int row = f4 >> 2;                // 0..127
            int kk4 = (f4 & 3) * 4;
            float4 av = *(const float4*)&x[(size_t)(by * 128 + row) * D_DIM + k0 + kk4];
            As[row][kk4 + 0] = av.x; As[row][kk4 + 1] = av.y;
            As[row][kk4 + 2] = av.z; As[row][kk4 + 3] = av.w;
        }
        {
            int kkb = tid >> 4;
            int col4 = (tid & 15) * 4;
            *(float4*)&Bs[kkb][col4] =
                *(const float4*)&w[(size_t)(k0 + kkb) * N3 + bx * 64 + col4];
        }
        __syncthreads();
#pragma unroll
        for (int kk = 0; kk < 16; ++kk) {
            float4 bv = *(const float4*)&Bs[kk][tx * 4];
#pragma unroll
            for (int i = 0; i < 8; ++i) {
                float a = As[ty * 8 + i][kk];
                c[i][0] = fmaf(a, bv.x, c[i][0]);
                c[i][1] = fmaf(a, bv.y, c[i][1]);
                c[i][2] = fmaf(a, bv.z, c[i][2]);
                c[i][3] = fmaf(a, bv.w, c[i][3]);
            }
        }
        __syncthreads();
    }

    int seg = bx >> 4;          // 0=q, 1=k, 2=v
    int h = bx & 15;
    int ncol = bx * 64 + tx * 4;
    float4 bias4 = *(const float4*)&bias[ncol];
    int nloc = h * 64 + tx * 4; // column within D for lora up-proj

    float4 arr[16];
    if (seg != 1) {
        const float* a2 = (seg == 0 ? qa2 : va2);
#pragma unroll
        for (int jj = 0; jj < 16; ++jj)
            arr[jj] = *(const float4*)&a2[jj * D_DIM + nloc];
    }

#pragma unroll
    for (int i = 0; i < 8; ++i) {
        int t = by * 128 + ty * 8 + i;
        float v0 = c[i][0] + bias4.x;
        float v1 = c[i][1] + bias4.y;
        float v2 = c[i][2] + bias4.z;
        float v3 = c[i][3] + bias4.w;
        if (seg != 1) {
            const float* trow = (seg == 0 ? tq : tv) + t * 16;
            float l0 = 0.f, l1 = 0.f, l2 = 0.f, l3 = 0.f;
#pragma unroll
            for (int jj = 0; jj < 16; ++jj) {
                float tvv = trow[jj];
                l0 = fmaf(tvv, arr[jj].x, l0);
                l1 = fmaf(tvv, arr[jj].y, l1);
                l2 = fmaf(tvv, arr[jj].z, l2);
                l3 = fmaf(tvv, arr[jj].w, l3);
            }
            v0 += 0.5f * l0; v1 += 0.5f * l1; v2 += 0.5f * l2; v3 += 0.5f * l3;
        }
        int b = t >> 11, sidx = t & 2047;
        size_t idx = (((size_t)(b * NH + h) * S_LEN + sidx) * HD) + tx * 4;
        if (seg == 0) {
            *(float4*)&qstage[idx] = make_float4(v0 * 0.125f, v1 * 0.125f,
                                                 v2 * 0.125f, v3 * 0.125f);
        } else if (seg == 1) {
            *(float4*)&pres[idx] = make_float4(v0, v1, v2, v3);
        } else {
            *(float4*)&pres[OUT_KV_ELEMS + idx] = make_float4(v0, v1, v2, v3);
        }
    }
}

// ---------------- K3: causal attention (flash, online softmax) ----------------
// Block = 256 threads (4 waves); 64 queries/block; wave w handles keys j ≡ w (mod 4).
__global__ __launch_bounds__(256) void attn_kernel(const float* __restrict__ q_s,
    const float* __restrict__ k_s, const float* __restrict__ v_s,
    float* __restrict__ a_s) {
    __shared__ float acc_sh[2][64][65];
    __shared__ float m_sh[2][64];
    __shared__ float l_sh[2][64];
    int qi = blockIdx.x;   // 0..31
    int bh = blockIdx.y;   // 0..31  (b*16+h)
    int tid = threadIdx.x;
    int lane = tid & 63;
    int w = tid >> 6;
    int i = qi * 64 + lane;

    const float4* qrow = (const float4*)(q_s + ((size_t)bh * S_LEN + i) * HD);
    float4 q4[16], a4[16];
#pragma unroll
    for (int u = 0; u < 16; ++u) { q4[u] = qrow[u]; a4[u] = make_float4(0.f, 0.f, 0.f, 0.f); }
    float m = -1e30f, l = 0.f;

    int jmax = qi * 64 + 63;
    for (int j = w; j <= jmax; j += 4) {
        const float4* krow = (const float4*)(k_s + ((size_t)bh * S_LEN + j) * HD);
        float s0 = 0.f, s1 = 0.f, s2 = 0.f, s3 = 0.f;
#pragma unroll
        for (int u = 0; u < 16; ++u) {
            float4 kv = krow[u];
            s0 = fmaf(q4[u].x, kv.x, s0);
            s1 = fmaf(q4[u].y, kv.y, s1);
            s2 = fmaf(q4[u].z, kv.z, s2);
            s3 = fmaf(q4[u].w, kv.w, s3);
        }
        float s = (s0 + s1) + (s2 + s3);
        bool valid = (j <= i);
        float se = valid ? s : -1e30f;
        float mn = fmaxf(m, se);
        if (__any(mn > m)) {
            float alpha = __expf(m - mn);
            l *= alpha;
#pragma unroll
            for (int u = 0; u < 16; ++u) {
                a4[u].x *= alpha; a4[u].y *= alpha; a4[u].z *= alpha; a4[u].w *= alpha;
            }
            m = mn;
        }
        float p = valid ? __expf(se - m) : 0.f;
        l += p;
        const float4* vrow = (const float4*)(v_s + ((size_t)bh * S_LEN + j) * HD);
#pragma unroll
        for (int u = 0; u < 16; ++u) {
            float4 vv = vrow[u];
            a4[u].x = fmaf(p, vv.x, a4[u].x);
            a4[u].y = fmaf(p, vv.y, a4[u].y);
            a4[u].z = fmaf(p, vv.z, a4[u].z);
            a4[u].w = fmaf(p, vv.w, a4[u].w);
        }
    }

    // tree merge: waves 2,3 -> slots 0,1 ; then wave1 -> slot0 ; wave0 finishes
    if (w >= 2) {
        int sl = w - 2;
        m_sh[sl][lane] = m; l_sh[sl][lane] = l;
        float* ap = &acc_sh[sl][lane][0];
#pragma unroll
        for (int u = 0; u < 16; ++u) {
            ap[4 * u + 0] = a4[u].x; ap[4 * u + 1] = a4[u].y;
            ap[4 * u + 2] = a4[u].z; ap[4 * u + 3] = a4[u].w;
        }
    }
    __syncthreads();
    if (w < 2) {
        float mo = m_sh[w][lane], lo = l_sh[w][lane];
        float mm = fmaxf(m, mo);
        float aS = __expf(m - mm), aO = __expf(mo - mm);
        l = aS * l + aO * lo;
        const float* ap = &acc_sh[w][lane][0];
#pragma unroll
        for (int u = 0; u < 16; ++u) {
            a4[u].x = aS * a4[u].x + aO * ap[4 * u + 0];
            a4[u].y = aS * a4[u].y + aO * ap[4 * u + 1];
            a4[u].z = aS * a4[u].z + aO * ap[4 * u + 2];
            a4[u].w = aS * a4[u].w + aO * ap[4 * u + 3];
        }
        m = mm;
    }
    __syncthreads();
    if (w == 1) {
        m_sh[0][lane] = m; l_sh[0][lane] = l;
        float* ap = &acc_sh[0][lane][0];
#pragma unroll
        for (int u = 0; u < 16; ++u) {
            ap[4 * u + 0] = a4[u].x; ap[4 * u + 1] = a4[u].y;
            ap[4 * u + 2] = a4[u].z; ap[4 * u + 3] = a4[u].w;
        }
    }
    __syncthreads();
    if (w == 0) {
        float mo = m_sh[0][lane], lo = l_sh[0][lane];
        float mm = fmaxf(m, mo);
        float aS = __expf(m - mm), aO = __expf(mo - mm);
        l = aS * l + aO * lo;
        const float* ap = &acc_sh[0][lane][0];
        float inv = 1.f / l;
        int b = bh >> 4, h = bh & 15;
        float4* orow = (float4*)(a_s + ((size_t)(b * S_LEN + i) * D_DIM) + h * HD);
#pragma unroll
        for (int u = 0; u < 16; ++u) {
            float ox = aS * a4[u].x + aO * ap[4 * u + 0];
            float oy = aS * a4[u].y + aO * ap[4 * u + 1];
            float oz = aS * a4[u].z + aO * ap[4 * u + 2];
            float ow = aS * a4[u].w + aO * ap[4 * u + 3];
            orow[u] = make_float4(ox * inv, oy * inv, oz * inv, ow * inv);
        }
    }
}

// ---------------- K4: out = a_s @ c_proj_w + c_proj_b  -> f32 ----------------
__global__ __launch_bounds__(256) void proj_kernel(const float* __restrict__ A,
    const float* __restrict__ w, const float* __restrict__ bias,
    float* __restrict__ outp) {
    __shared__ float As[128][17];
    __shared__ float Bs[16][64];
    int bx = blockIdx.x;   // 0..15
    int by = blockIdx.y;   // 0..31
    int tid = threadIdx.x;
    int tx = tid & 15, ty = tid >> 4;

    float c[8][4];
#pragma unroll
    for (int i = 0; i < 8; ++i)
#pragma unroll
        for (int j = 0; j < 4; ++j) c[i][j] = 0.f;

    for (int k0 = 0; k0 < D_DIM; k0 += 16) {
#pragma unroll
        for (int u = 0; u < 2; ++u) {
            int f4 = tid + 256 * u;
            int row = f4 >> 2;
            int kk4 = (f4 & 3) * 4;
            float4 av = *(const float4*)&A[(size_t)(by * 128 + row) * D_DIM + k0 + kk4];
            As[row][kk4 + 0] = av.x; As[row][kk4 + 1] = av.y;
            As[row][kk4 + 2] = av.z; As[row][kk4 + 3] = av.w;
        }
        {
            int kkb = tid >> 4;
            int col4 = (tid & 15) * 4;
            *(float4*)&Bs[kkb][col4] =
                *(const float4*)&w[(size_t)(k0 + kkb) * D_DIM + bx * 64 + col4];
        }
        __syncthreads();
#pragma unroll
        for (int kk = 0; kk < 16; ++kk) {
            float4 bv = *(const float4*)&Bs[kk][tx * 4];
#pragma unroll
            for (int i = 0; i < 8; ++i) {
                float a = As[ty * 8 + i][kk];
                c[i][0] = fmaf(a, bv.x, c[i][0]);
                c[i][1] = fmaf(a, bv.y, c[i][1]);
                c[i][2] = fmaf(a, bv.z, c[i][2]);
                c[i][3] = fmaf(a, bv.w, c[i][3]);
            }
        }
        __syncthreads();
    }

    int ncol = bx * 64 + tx * 4;
    float4 bias4 = *(const float4*)&bias[ncol];
#pragma unroll
    for (int i = 0; i < 8; ++i) {
        int t = by * 128 + ty * 8 + i;
        *(float4*)&outp[(size_t)t * D_DIM + ncol] =
            make_float4(c[i][0] + bias4.x, c[i][1] + bias4.y,
                        c[i][2] + bias4.z, c[i][3] + bias4.w);
    }
}

extern "C" void kernel_launch(void* const* d_in, const int* in_sizes, int n_in,
                              void* d_out, int out_size, void* d_ws, size_t ws_size,
                              hipStream_t stream) {
    const float* x        = (const float*)d_in[0];
    const float* c_attn_w = (const float*)d_in[1];
    const float* c_attn_b = (const float*)d_in[2];
    const float* c_proj_w = (const float*)d_in[3];
    const float* c_proj_b = (const float*)d_in[4];
    const float* q_a1     = (const float*)d_in[5];
    const float* q_a2     = (const float*)d_in[6];
    const float* v_a1     = (const float*)d_in[7];
    const float* v_a2     = (const float*)d_in[8];

    float* outf   = (float*)d_out;
    float* qstage = outf;                  // a-region reused as f32 q staging [B,H,S,hd]
    float* pres   = outf + OUT_A_ELEMS;    // present [2,B,H,S,hd] f32

    float* wsf = (float*)d_ws;
    float* tq  = wsf;                      // 4096*16 f32
    float* tv  = tq + 65536;
    float* a_s = tv + 65536;               // [B,S,D] f32 (16 MB)

    lora1_kernel<<<dim3(T_TOK), dim3(64), 0, stream>>>(x, q_a1, v_a1, tq, tv);
    qkv_kernel<<<dim3(48, 32), dim3(256), 0, stream>>>(x, c_attn_w, c_attn_b,
        q_a2, v_a2, tq, tv, qstage, pres);
    attn_kernel<<<dim3(32, 32), dim3(256), 0, stream>>>(qstage, pres, pres + OUT_KV_ELEMS, a_s);
    proj_kernel<<<dim3(16, 32), dim3(256), 0, stream>>>(a_s, c_proj_w, c_proj_b, outf);
}

// Round 9
// 1004.736 us; speedup vs baseline: 2.5850x; 2.5850x over previous
//
#include <hip/hip_runtime.h>
#include <hip/hip_bf16.h>

#define T_TOK 4096   // B*S
#define D_DIM 1024
#define N3    3072
#define S_LEN 2048
#define NH    16
#define HD    64

#define OUT_A_ELEMS   4194304   // B*S*D   (f32 elements)
#define OUT_KV_ELEMS  4194304   // B*H*S*hd

// ---------------- K1: lora down-proj  tq = x@q_a1, tv = x@v_a1  ----------------
__global__ __launch_bounds__(64) void lora1_kernel(const float* __restrict__ x,
    const float* __restrict__ qa1, const float* __restrict__ va1,
    float* __restrict__ tq, float* __restrict__ tv) {
    int t = blockIdx.x;
    int lane = threadIdx.x;
    if (lane >= 32) return;
    const float* a1 = (lane < 16) ? qa1 : va1;
    int col = lane & 15;
    const float* xr = x + (size_t)t * D_DIM;
    float acc = 0.f;
#pragma unroll 4
    for (int k = 0; k < D_DIM; ++k)
        acc = fmaf(xr[k], a1[k * 16 + col], acc);
    if (lane < 16) tq[t * 16 + col] = acc;
    else           tv[t * 16 + col] = acc;
}

// ------ K2: qkv = x@W + b (+ lora up); q (pre-scaled 1/8) -> qstage, k/v -> present (f32)
__global__ __launch_bounds__(256) void qkv_kernel(const float* __restrict__ x,
    const float* __restrict__ w, const float* __restrict__ bias,
    const float* __restrict__ qa2, const float* __restrict__ va2,
    const float* __restrict__ tq, const float* __restrict__ tv,
    float* __restrict__ qstage,   // [B,H,S,hd] f32 (aliases a-region of d_out)
    float* __restrict__ pres) {   // [2,B,H,S,hd] f32 (present region of d_out)
    __shared__ float As[128][17];
    __shared__ float Bs[16][64];
    int bx = blockIdx.x;   // 0..47
    int by = blockIdx.y;   // 0..31
    int tid = threadIdx.x;
    int tx = tid & 15, ty = tid >> 4;

    float c[8][4];
#pragma unroll
    for (int i = 0; i < 8; ++i)
#pragma unroll
        for (int j = 0; j < 4; ++j) c[i][j] = 0.f;

    for (int k0 = 0; k0 < D_DIM; k0 += 16) {
#pragma unroll
        for (int u = 0; u < 2; ++u) {
            int f4 = tid + 256 * u;           // 0..511
            int row = f4 >> 2;                // 0..127
            int kk4 = (f4 & 3) * 4;
            float4 av = *(const float4*)&x[(size_t)(by * 128 + row) * D_DIM + k0 + kk4];
            As[row][kk4 + 0] = av.x; As[row][kk4 + 1] = av.y;
            As[row][kk4 + 2] = av.z; As[row][kk4 + 3] = av.w;
        }
        {
            int kkb = tid >> 4;
            int col4 = (tid & 15) * 4;
            *(float4*)&Bs[kkb][col4] =
                *(const float4*)&w[(size_t)(k0 + kkb) * N3 + bx * 64 + col4];
        }
        __syncthreads();
#pragma unroll
        for (int kk = 0; kk < 16; ++kk) {
            float4 bv = *(const float4*)&Bs[kk][tx * 4];
#pragma unroll
            for (int i = 0; i < 8; ++i) {
                float a = As[ty * 8 + i][kk];
                c[i][0] = fmaf(a, bv.x, c[i][0]);
                c[i][1] = fmaf(a, bv.y, c[i][1]);
                c[i][2] = fmaf(a, bv.z, c[i][2]);
                c[i][3] = fmaf(a, bv.w, c[i][3]);
            }
        }
        __syncthreads();
    }

    int seg = bx >> 4;          // 0=q, 1=k, 2=v
    int h = bx & 15;
    int ncol = bx * 64 + tx * 4;
    float4 bias4 = *(const float4*)&bias[ncol];
    int nloc = h * 64 + tx * 4;

    float4 arr[16];
    if (seg != 1) {
        const float* a2 = (seg == 0 ? qa2 : va2);
#pragma unroll
        for (int jj = 0; jj < 16; ++jj)
            arr[jj] = *(const float4*)&a2[jj * D_DIM + nloc];
    }

#pragma unroll
    for (int i = 0; i < 8; ++i) {
        int t = by * 128 + ty * 8 + i;
        float v0 = c[i][0] + bias4.x;
        float v1 = c[i][1] + bias4.y;
        float v2 = c[i][2] + bias4.z;
        float v3 = c[i][3] + bias4.w;
        if (seg != 1) {
            const float* trow = (seg == 0 ? tq : tv) + t * 16;
            float l0 = 0.f, l1 = 0.f, l2 = 0.f, l3 = 0.f;
#pragma unroll
            for (int jj = 0; jj < 16; ++jj) {
                float tvv = trow[jj];
                l0 = fmaf(tvv, arr[jj].x, l0);
                l1 = fmaf(tvv, arr[jj].y, l1);
                l2 = fmaf(tvv, arr[jj].z, l2);
                l3 = fmaf(tvv, arr[jj].w, l3);
            }
            v0 += 0.5f * l0; v1 += 0.5f * l1; v2 += 0.5f * l2; v3 += 0.5f * l3;
        }
        int b = t >> 11, sidx = t & 2047;
        size_t idx = (((size_t)(b * NH + h) * S_LEN + sidx) * HD) + tx * 4;
        if (seg == 0) {
            *(float4*)&qstage[idx] = make_float4(v0 * 0.125f, v1 * 0.125f,
                                                 v2 * 0.125f, v3 * 0.125f);
        } else if (seg == 1) {
            *(float4*)&pres[idx] = make_float4(v0, v1, v2, v3);
        } else {
            *(float4*)&pres[OUT_KV_ELEMS + idx] = make_float4(v0, v1, v2, v3);
        }
    }
}

// ---------------- K3: flash attention, LDS-GEMM tiles ----------------
// Block = 256 threads; 64 queries/block; K-tiles of 64 staged in LDS.
// Thread (tx,ty): 4x4 register tile; rows = queries ty*4+r, cols vary by phase.
#define LSTR 68
__global__ __launch_bounds__(256) void attn_kernel(const float* __restrict__ q_s,
    const float* __restrict__ k_s, const float* __restrict__ v_s,
    float* __restrict__ a_s) {
    __shared__ float Qt[64][LSTR];   // [dim][query]
    __shared__ float KP[64][LSTR];   // phase 1: [dim][key]; phase 2: P[query][key]
    __shared__ float Vs[64][LSTR];   // [key][dim]
    int bh = blockIdx.x;             // 0..31
    int qi = 31 - blockIdx.y;        // longest blocks dispatched first
    int tid = threadIdx.x;
    int tx = tid & 15, ty = tid >> 4;

    // stage Q tile transposed: Qt[d][q]
#pragma unroll
    for (int qq = 0; qq < 4; ++qq) {
        int q  = qq * 16 + (tid >> 4);
        int d4 = (tid & 15) * 4;
        float4 v = *(const float4*)&q_s[((size_t)bh * S_LEN + qi * 64 + q) * HD + d4];
        Qt[d4 + 0][q] = v.x; Qt[d4 + 1][q] = v.y;
        Qt[d4 + 2][q] = v.z; Qt[d4 + 3][q] = v.w;
    }

    float o[4][4];
#pragma unroll
    for (int r = 0; r < 4; ++r)
#pragma unroll
        for (int c = 0; c < 4; ++c) o[r][c] = 0.f;
    float mrow[4] = {-1e30f, -1e30f, -1e30f, -1e30f};
    float lrow[4] = {0.f, 0.f, 0.f, 0.f};

    for (int kt = 0; kt <= qi; ++kt) {
        __syncthreads();   // prev PV reads done before restaging
        // stage K transposed + V natural
#pragma unroll
        for (int kk2 = 0; kk2 < 4; ++kk2) {
            int k  = kk2 * 16 + (tid >> 4);
            int d4 = (tid & 15) * 4;
            size_t rowoff = ((size_t)bh * S_LEN + kt * 64 + k) * HD + d4;
            float4 kv4 = *(const float4*)&k_s[rowoff];
            KP[d4 + 0][k] = kv4.x; KP[d4 + 1][k] = kv4.y;
            KP[d4 + 2][k] = kv4.z; KP[d4 + 3][k] = kv4.w;
            float4 vv4 = *(const float4*)&v_s[rowoff];
            *(float4*)&Vs[k][d4] = vv4;
        }
        __syncthreads();

        // scores: s[r][c] = sum_d Qt[d][ty*4+r] * KP[d][tx*4+c]
        float s[4][4];
#pragma unroll
        for (int r = 0; r < 4; ++r)
#pragma unroll
            for (int c = 0; c < 4; ++c) s[r][c] = 0.f;
#pragma unroll 8
        for (int d = 0; d < 64; ++d) {
            float4 qv = *(const float4*)&Qt[d][ty * 4];
            float4 kv = *(const float4*)&KP[d][tx * 4];
            float qa[4] = {qv.x, qv.y, qv.z, qv.w};
            float ka[4] = {kv.x, kv.y, kv.z, kv.w};
#pragma unroll
            for (int r = 0; r < 4; ++r)
#pragma unroll
                for (int c = 0; c < 4; ++c)
                    s[r][c] = fmaf(qa[r], ka[c], s[r][c]);
        }
        if (kt == qi) {   // causal mask on the diagonal tile
#pragma unroll
            for (int r = 0; r < 4; ++r)
#pragma unroll
                for (int c = 0; c < 4; ++c)
                    if (tx * 4 + c > ty * 4 + r) s[r][c] = -1e30f;
        }
        __syncthreads();   // all KP(K) reads done before overwrite with P

        // online softmax per row + write P into KP
        float p[4][4];
#pragma unroll
        for (int r = 0; r < 4; ++r) {
            float mx = fmaxf(fmaxf(s[r][0], s[r][1]), fmaxf(s[r][2], s[r][3]));
            mx = fmaxf(mx, __shfl_xor(mx, 1));
            mx = fmaxf(mx, __shfl_xor(mx, 2));
            mx = fmaxf(mx, __shfl_xor(mx, 4));
            mx = fmaxf(mx, __shfl_xor(mx, 8));
            float mn = fmaxf(mrow[r], mx);
            float alpha = __expf(mrow[r] - mn);
            mrow[r] = mn;
            float rs = 0.f;
#pragma unroll
            for (int c = 0; c < 4; ++c) {
                p[r][c] = __expf(s[r][c] - mn);
                rs += p[r][c];
            }
            rs += __shfl_xor(rs, 1);
            rs += __shfl_xor(rs, 2);
            rs += __shfl_xor(rs, 4);
            rs += __shfl_xor(rs, 8);
            lrow[r] = lrow[r] * alpha + rs;
#pragma unroll
            for (int c = 0; c < 4; ++c) o[r][c] *= alpha;
            *(float4*)&KP[ty * 4 + r][tx * 4] =
                make_float4(p[r][0], p[r][1], p[r][2], p[r][3]);
        }
        __syncthreads();   // P visible

        // PV: o[r][c] += sum_k P[ty*4+r][k] * Vs[k][tx*4+c]
#pragma unroll 8
        for (int k = 0; k < 64; ++k) {
            float4 vv = *(const float4*)&Vs[k][tx * 4];
            float va[4] = {vv.x, vv.y, vv.z, vv.w};
#pragma unroll
            for (int r = 0; r < 4; ++r) {
                float pr = KP[ty * 4 + r][k];
#pragma unroll
                for (int c = 0; c < 4; ++c)
                    o[r][c] = fmaf(pr, va[c], o[r][c]);
            }
        }
    }

    int b = bh >> 4, h = bh & 15;
#pragma unroll
    for (int r = 0; r < 4; ++r) {
        int i = qi * 64 + ty * 4 + r;
        float inv = 1.f / lrow[r];
        *(float4*)&a_s[((size_t)(b * S_LEN + i)) * D_DIM + h * HD + tx * 4] =
            make_float4(o[r][0] * inv, o[r][1] * inv, o[r][2] * inv, o[r][3] * inv);
    }
}

// ---------------- K4: out = a_s @ c_proj_w + c_proj_b  -> f32 ----------------
__global__ __launch_bounds__(256) void proj_kernel(const float* __restrict__ A,
    const float* __restrict__ w, const float* __restrict__ bias,
    float* __restrict__ outp) {
    __shared__ float As[128][17];
    __shared__ float Bs[16][64];
    int bx = blockIdx.x;   // 0..15
    int by = blockIdx.y;   // 0..31
    int tid = threadIdx.x;
    int tx = tid & 15, ty = tid >> 4;

    float c[8][4];
#pragma unroll
    for (int i = 0; i < 8; ++i)
#pragma unroll
        for (int j = 0; j < 4; ++j) c[i][j] = 0.f;

    for (int k0 = 0; k0 < D_DIM; k0 += 16) {
#pragma unroll
        for (int u = 0; u < 2; ++u) {
            int f4 = tid + 256 * u;
            int row = f4 >> 2;
            int kk4 = (f4 & 3) * 4;
            float4 av = *(const float4*)&A[(size_t)(by * 128 + row) * D_DIM + k0 + kk4];
            As[row][kk4 + 0] = av.x; As[row][kk4 + 1] = av.y;
            As[row][kk4 + 2] = av.z; As[row][kk4 + 3] = av.w;
        }
        {
            int kkb = tid >> 4;
            int col4 = (tid & 15) * 4;
            *(float4*)&Bs[kkb][col4] =
                *(const float4*)&w[(size_t)(k0 + kkb) * D_DIM + bx * 64 + col4];
        }
        __syncthreads();
#pragma unroll
        for (int kk = 0; kk < 16; ++kk) {
            float4 bv = *(const float4*)&Bs[kk][tx * 4];
#pragma unroll
            for (int i = 0; i < 8; ++i) {
                float a = As[ty * 8 + i][kk];
                c[i][0] = fmaf(a, bv.x, c[i][0]);
                c[i][1] = fmaf(a, bv.y, c[i][1]);
                c[i][2] = fmaf(a, bv.z, c[i][2]);
                c[i][3] = fmaf(a, bv.w, c[i][3]);
            }
        }
        __syncthreads();
    }

    int ncol = bx * 64 + tx * 4;
    float4 bias4 = *(const float4*)&bias[ncol];
#pragma unroll
    for (int i = 0; i < 8; ++i) {
        int t = by * 128 + ty * 8 + i;
        *(float4*)&outp[(size_t)t * D_DIM + ncol] =
            make_float4(c[i][0] + bias4.x, c[i][1] + bias4.y,
                        c[i][2] + bias4.z, c[i][3] + bias4.w);
    }
}

extern "C" void kernel_launch(void* const* d_in, const int* in_sizes, int n_in,
                              void* d_out, int out_size, void* d_ws, size_t ws_size,
                              hipStream_t stream) {
    const float* x        = (const float*)d_in[0];
    const float* c_attn_w = (const float*)d_in[1];
    const float* c_attn_b = (const float*)d_in[2];
    const float* c_proj_w = (const float*)d_in[3];
    const float* c_proj_b = (const float*)d_in[4];
    const float* q_a1     = (const float*)d_in[5];
    const float* q_a2     = (const float*)d_in[6];
    const float* v_a1     = (const float*)d_in[7];
    const float* v_a2     = (const float*)d_in[8];

    float* outf   = (float*)d_out;
    float* qstage = outf;                  // a-region reused as f32 q staging [B,H,S,hd]
    float* pres   = outf + OUT_A_ELEMS;    // present [2,B,H,S,hd] f32

    float* wsf = (float*)d_ws;
    float* tq  = wsf;                      // 4096*16 f32
    float* tv  = tq + 65536;
    float* a_s = tv + 65536;               // [B,S,D] f32 (16 MB)

    lora1_kernel<<<dim3(T_TOK), dim3(64), 0, stream>>>(x, q_a1, v_a1, tq, tv);
    qkv_kernel<<<dim3(48, 32), dim3(256), 0, stream>>>(x, c_attn_w, c_attn_b,
        q_a2, v_a2, tq, tv, qstage, pres);
    attn_kernel<<<dim3(32, 32), dim3(256), 0, stream>>>(qstage, pres, pres + OUT_KV_ELEMS, a_s);
    proj_kernel<<<dim3(16, 32), dim3(256), 0, stream>>>(a_s, c_proj_w, c_proj_b, outf);
}